// Round 1
// baseline (1924.945 us; speedup 1.0000x reference)
//
#include <hip/hip_runtime.h>

// GCN: 3x (x = silu(Dinv^1/2 A Dinv^1/2 (x W) + b)) -> mean-pool per graph -> relu(pooled@Wro+bro) -> log_softmax
// Algebra: y = (x@W) * dinv[row];  out[c] = dinv[c]*(sum_{edges r->c} y[r] + y[c]) + b;  x' = silu(out)

__global__ void k_deg(const int* __restrict__ col, int E, int* __restrict__ deg) {
    int e = blockIdx.x * blockDim.x + threadIdx.x;
    if (e < E) atomicAdd(&deg[col[e]], 1);
}

__global__ void k_dinv(const int* __restrict__ deg, int N, float* __restrict__ dinv) {
    int i = blockIdx.x * blockDim.x + threadIdx.x;
    if (i < N) dinv[i] = rsqrtf((float)deg[i] + 1.0f);  // +1 = self loop
}

// y[row] = (x[row] @ W) * dinv[row]; 4 rows per 256-thread block, W staged in LDS.
__global__ void k_gemm_scale(const float* __restrict__ x, const float* __restrict__ W,
                             const float* __restrict__ dinv, float* __restrict__ y, int N) {
    __shared__ float sW[64 * 64];
    __shared__ float sx[4 * 64];
    int tid = threadIdx.x;
    for (int k = tid; k < 64 * 64; k += 256) sW[k] = W[k];
    int r = tid >> 6;      // 0..3
    int j = tid & 63;      // 0..63
    int row = blockIdx.x * 4 + r;
    if (row < N) sx[r * 64 + j] = x[(size_t)row * 64 + j];
    __syncthreads();
    if (row < N) {
        float acc = 0.f;
#pragma unroll
        for (int k = 0; k < 64; ++k) acc += sx[r * 64 + k] * sW[k * 64 + j];
        y[(size_t)row * 64 + j] = acc * dinv[row];
    }
}

// One wave per edge (grid-stride): lane j does agg[col][j] += y[row][j]
__global__ void k_scatter(const int* __restrict__ row, const int* __restrict__ col,
                          const float* __restrict__ y, float* __restrict__ agg, int E) {
    int lane = threadIdx.x & 63;
    int wave = (blockIdx.x * blockDim.x + threadIdx.x) >> 6;
    int nwaves = (gridDim.x * blockDim.x) >> 6;
    for (int e = wave; e < E; e += nwaves) {
        int r = row[e], c = col[e];
        atomicAdd(&agg[(size_t)c * 64 + lane], y[(size_t)r * 64 + lane]);
    }
}

// x'[i][j] = silu(dinv[i]*(agg[i][j] + y[i][j]) + b[j]), in-place into agg
__global__ void k_update(float* __restrict__ agg, const float* __restrict__ y,
                         const float* __restrict__ dinv, const float* __restrict__ b, int N) {
    int idx = blockIdx.x * blockDim.x + threadIdx.x;
    if (idx < N * 64) {
        int i = idx >> 6, j = idx & 63;
        float v = dinv[i] * (agg[idx] + y[idx]) + b[j];
        agg[idx] = v / (1.f + __expf(-v));
    }
}

__global__ void k_pool(const float* __restrict__ x, const int* __restrict__ batch,
                       float* __restrict__ sums, float* __restrict__ cnts, int N) {
    int idx = blockIdx.x * blockDim.x + threadIdx.x;
    if (idx < N * 64) {
        int i = idx >> 6, j = idx & 63;
        int g = batch[i];
        atomicAdd(&sums[(size_t)g * 64 + j], x[idx]);
        if (j == 0) atomicAdd(&cnts[g], 1.0f);
    }
}

// One 64-thread block per graph: mean, readout linear+relu, log_softmax
__global__ void k_readout(const float* __restrict__ sums, const float* __restrict__ cnts,
                          const float* __restrict__ Wro, const float* __restrict__ bro,
                          float* __restrict__ out, int C) {
    int g = blockIdx.x;
    __shared__ float sp[64];
    __shared__ float sl[32];
    int j = threadIdx.x;
    float cnt = fmaxf(cnts[g], 1.0f);
    sp[j] = sums[(size_t)g * 64 + j] / cnt;
    __syncthreads();
    if (j < C) {
        float acc = bro[j];
        for (int k = 0; k < 64; ++k) acc += sp[k] * Wro[k * C + j];
        sl[j] = fmaxf(acc, 0.f);
    }
    __syncthreads();
    if (j == 0) {
        float m = -1e30f;
        for (int c = 0; c < C; ++c) m = fmaxf(m, sl[c]);
        float s = 0.f;
        for (int c = 0; c < C; ++c) s += __expf(sl[c] - m);
        float lse = m + __logf(s);
        for (int c = 0; c < C; ++c) out[g * C + c] = sl[c] - lse;
    }
}

extern "C" void kernel_launch(void* const* d_in, const int* in_sizes, int n_in,
                              void* d_out, int out_size, void* d_ws, size_t ws_size,
                              hipStream_t stream) {
    const float* x    = (const float*)d_in[0];
    const int*   ei   = (const int*)d_in[1];
    const int*   batch= (const int*)d_in[2];
    const float* W[3] = {(const float*)d_in[4], (const float*)d_in[6], (const float*)d_in[8]};
    const float* b[3] = {(const float*)d_in[5], (const float*)d_in[7], (const float*)d_in[9]};
    const float* Wro  = (const float*)d_in[10];
    const float* bro  = (const float*)d_in[11];

    int N = in_sizes[2];          // batch is [N]
    int E = in_sizes[1] / 2;      // edge_index is [2, E]
    int C = in_sizes[10] / 64;    // Wro is [64, C]
    int G = out_size / C;

    const int* row = ei;          // sources
    const int* col = ei + E;      // targets

    char* ws = (char*)d_ws;
    float* dinv = (float*)ws;  ws += (size_t)N * sizeof(float);
    int*   deg  = (int*)ws;    ws += (size_t)N * sizeof(int);
    float* y    = (float*)ws;  ws += (size_t)N * 64 * sizeof(float);
    float* agg  = (float*)ws;  ws += (size_t)N * 64 * sizeof(float);
    float* sums = (float*)ws;  ws += (size_t)G * 64 * sizeof(float);
    float* cnts = (float*)ws;  ws += (size_t)G * sizeof(float);

    hipMemsetAsync(deg, 0, (size_t)N * sizeof(int), stream);
    k_deg<<<(E + 255) / 256, 256, 0, stream>>>(col, E, deg);
    k_dinv<<<(N + 255) / 256, 256, 0, stream>>>(deg, N, dinv);

    const float* xin = x;
    for (int l = 0; l < 3; ++l) {
        k_gemm_scale<<<(N + 3) / 4, 256, 0, stream>>>(xin, W[l], dinv, y, N);
        hipMemsetAsync(agg, 0, (size_t)N * 64 * sizeof(float), stream);
        k_scatter<<<2048, 256, 0, stream>>>(row, col, y, agg, E);
        k_update<<<((size_t)N * 64 + 255) / 256, 256, 0, stream>>>(agg, y, dinv, b[l], N);
        xin = agg;
    }

    hipMemsetAsync(sums, 0, (size_t)(G * 64 + G) * sizeof(float), stream);  // sums+cnts contiguous
    k_pool<<<((size_t)N * 64 + 255) / 256, 256, 0, stream>>>(agg, batch, sums, cnts, N);
    k_readout<<<G, 64, 0, stream>>>(sums, cnts, Wro, bro, (float*)d_out, C);
}

// Round 2
// 1528.883 us; speedup vs baseline: 1.2591x; 1.2591x over previous
//
#include <hip/hip_runtime.h>

// GCN: 3x (x = silu(Dinv A Dinv (x W) + b)) -> mean-pool -> relu(pooled@Wro+bro) -> log_softmax
// y = (x@W)*dinv[row];  out[c] = dinv[c]*(sum_{r->c} y[r] + y[c]) + b;  x' = silu(out)
// Edge aggregation via CSR (built once): srcs sorted by target node.

__global__ void k_deg(const int* __restrict__ col, int E, int* __restrict__ deg) {
    int e = blockIdx.x * blockDim.x + threadIdx.x;
    if (e < E) atomicAdd(&deg[col[e]], 1);
}

__global__ void k_dinv(const int* __restrict__ deg, int N, float* __restrict__ dinv) {
    int i = blockIdx.x * blockDim.x + threadIdx.x;
    if (i < N) dinv[i] = rsqrtf((float)deg[i] + 1.0f);  // +1 = self loop
}

// ---- exclusive scan of deg -> starts (3 kernels, chunk=256) ----
__global__ void k_scan1(const int* __restrict__ deg, int N, int* __restrict__ starts,
                        int* __restrict__ bsums) {
    __shared__ int s[256];
    int tid = threadIdx.x;
    int i = blockIdx.x * 256 + tid;
    int v = (i < N) ? deg[i] : 0;
    s[tid] = v;
    __syncthreads();
    for (int off = 1; off < 256; off <<= 1) {
        int t = (tid >= off) ? s[tid - off] : 0;
        __syncthreads();
        s[tid] += t;
        __syncthreads();
    }
    if (i < N) starts[i] = s[tid] - v;          // exclusive within block
    if (tid == 255) bsums[blockIdx.x] = s[255]; // block total
}

__global__ void k_scan2(int* __restrict__ bsums, int B) {  // B <= 512, single block
    __shared__ int s[512];
    int tid = threadIdx.x;
    int v = (tid < B) ? bsums[tid] : 0;
    s[tid] = v;
    __syncthreads();
    for (int off = 1; off < 512; off <<= 1) {
        int t = (tid >= off) ? s[tid - off] : 0;
        __syncthreads();
        s[tid] += t;
        __syncthreads();
    }
    if (tid < B) bsums[tid] = s[tid] - v;       // exclusive block offsets
}

__global__ void k_scan3(int* __restrict__ starts, const int* __restrict__ bsums,
                        int N, int E, int* __restrict__ cursor) {
    int i = blockIdx.x * 256 + threadIdx.x;
    if (i < N) {
        int v = starts[i] + bsums[blockIdx.x];
        starts[i] = v;
        cursor[i] = v;
    }
    if (blockIdx.x == 0 && threadIdx.x == 0) starts[N] = E;
}

__global__ void k_bucket(const int* __restrict__ row, const int* __restrict__ col, int E,
                         int* __restrict__ cursor, int* __restrict__ srcs) {
    int e = blockIdx.x * blockDim.x + threadIdx.x;
    if (e < E) {
        int pos = atomicAdd(&cursor[col[e]], 1);
        srcs[pos] = row[e];
    }
}

// y[row] = (x[row] @ W) * dinv[row]; 16 rows per 256-thread block, W staged in LDS.
__global__ void k_gemm_scale(const float* __restrict__ x, const float* __restrict__ W,
                             const float* __restrict__ dinv, float* __restrict__ y, int N) {
    __shared__ float sW[64 * 64];
    __shared__ float sx[16 * 64];
    int tid = threadIdx.x;
    for (int k = tid; k < 64 * 64; k += 256) sW[k] = W[k];
    int r = tid >> 6;      // 0..3
    int j = tid & 63;      // 0..63
    int base = blockIdx.x * 16;
    for (int rr = r; rr < 16; rr += 4) {
        int row = base + rr;
        sx[rr * 64 + j] = (row < N) ? x[(size_t)row * 64 + j] : 0.f;
    }
    __syncthreads();
    float acc0 = 0.f, acc1 = 0.f, acc2 = 0.f, acc3 = 0.f;
#pragma unroll
    for (int k = 0; k < 64; ++k) {
        float w = sW[k * 64 + j];
        acc0 += sx[(r     ) * 64 + k] * w;
        acc1 += sx[(r +  4) * 64 + k] * w;
        acc2 += sx[(r +  8) * 64 + k] * w;
        acc3 += sx[(r + 12) * 64 + k] * w;
    }
    int row0 = base + r;
    if (row0      < N) y[(size_t)(row0     ) * 64 + j] = acc0 * dinv[row0];
    if (row0 +  4 < N) y[(size_t)(row0 +  4) * 64 + j] = acc1 * dinv[row0 + 4];
    if (row0 +  8 < N) y[(size_t)(row0 +  8) * 64 + j] = acc2 * dinv[row0 + 8];
    if (row0 + 12 < N) y[(size_t)(row0 + 12) * 64 + j] = acc3 * dinv[row0 + 12];
}

// One wave per node: acc = y[node] + sum_{e} y[srcs[e]]; out = silu(dinv*acc + b)
__global__ void k_agg(const int* __restrict__ starts, const int* __restrict__ srcs,
                      const float* __restrict__ y, const float* __restrict__ dinv,
                      const float* __restrict__ b, float* __restrict__ xout, int N) {
    int lane = threadIdx.x & 63;
    int node = (blockIdx.x * blockDim.x + threadIdx.x) >> 6;
    if (node >= N) return;
    float acc = y[(size_t)node * 64 + lane];
    int s = starts[node], t = starts[node + 1];
    int e = s;
    for (; e + 3 < t; e += 4) {
        int r0 = srcs[e], r1 = srcs[e + 1], r2 = srcs[e + 2], r3 = srcs[e + 3];
        float v0 = y[(size_t)r0 * 64 + lane];
        float v1 = y[(size_t)r1 * 64 + lane];
        float v2 = y[(size_t)r2 * 64 + lane];
        float v3 = y[(size_t)r3 * 64 + lane];
        acc += (v0 + v1) + (v2 + v3);
    }
    for (; e < t; ++e) acc += y[(size_t)srcs[e] * 64 + lane];
    float v = dinv[node] * acc + b[lane];
    xout[(size_t)node * 64 + lane] = v / (1.f + __expf(-v));
}

// One block per graph: binary-search segment, mean-pool, readout, log_softmax
__global__ void k_pool_readout(const float* __restrict__ x, const int* __restrict__ batch, int N,
                               const float* __restrict__ Wro, const float* __restrict__ bro,
                               float* __restrict__ out, int C) {
    int g = blockIdx.x;
    int tid = threadIdx.x, wave = tid >> 6, lane = tid & 63;
    __shared__ float part[4][64];
    __shared__ float pooled[64];
    __shared__ float logits[32];
    // lower_bound(batch, g) and lower_bound(batch, g+1)
    int lo = 0, hi_b = N;
    while (lo < hi_b) { int m = (lo + hi_b) >> 1; if (batch[m] < g) lo = m + 1; else hi_b = m; }
    int lo2 = lo, hi2 = N;
    while (lo2 < hi2) { int m = (lo2 + hi2) >> 1; if (batch[m] < g + 1) lo2 = m + 1; else hi2 = m; }
    int hi = lo2;
    float acc = 0.f;
    for (int i = lo + wave; i < hi; i += 4) acc += x[(size_t)i * 64 + lane];
    part[wave][lane] = acc;
    __syncthreads();
    if (wave == 0) {
        float cnt = fmaxf((float)(hi - lo), 1.0f);
        pooled[lane] = (part[0][lane] + part[1][lane] + part[2][lane] + part[3][lane]) / cnt;
    }
    __syncthreads();
    if (tid < C) {
        float a = bro[tid];
        for (int k = 0; k < 64; ++k) a += pooled[k] * Wro[k * C + tid];
        logits[tid] = fmaxf(a, 0.f);
    }
    __syncthreads();
    if (tid == 0) {
        float m = -1e30f;
        for (int c = 0; c < C; ++c) m = fmaxf(m, logits[c]);
        float s = 0.f;
        for (int c = 0; c < C; ++c) s += __expf(logits[c] - m);
        float lse = m + __logf(s);
        for (int c = 0; c < C; ++c) out[g * C + c] = logits[c] - lse;
    }
}

extern "C" void kernel_launch(void* const* d_in, const int* in_sizes, int n_in,
                              void* d_out, int out_size, void* d_ws, size_t ws_size,
                              hipStream_t stream) {
    const float* x    = (const float*)d_in[0];
    const int*   ei   = (const int*)d_in[1];
    const int*   batch= (const int*)d_in[2];
    const float* W[3] = {(const float*)d_in[4], (const float*)d_in[6], (const float*)d_in[8]};
    const float* b[3] = {(const float*)d_in[5], (const float*)d_in[7], (const float*)d_in[9]};
    const float* Wro  = (const float*)d_in[10];
    const float* bro  = (const float*)d_in[11];

    int N = in_sizes[2];          // batch is [N]
    int E = in_sizes[1] / 2;      // edge_index is [2, E]
    int C = in_sizes[10] / 64;    // Wro is [64, C]
    int G = out_size / C;

    const int* row = ei;          // sources
    const int* col = ei + E;      // targets

    char* ws = (char*)d_ws;
    float* dinv   = (float*)ws;  ws += (size_t)N * sizeof(float);
    int*   deg    = (int*)ws;    ws += (size_t)N * sizeof(int);        // reused as cursor
    int*   starts = (int*)ws;    ws += (size_t)(N + 1) * sizeof(int);
    int*   bsums  = (int*)ws;    ws += 512 * sizeof(int);
    int*   srcs   = (int*)ws;    ws += (size_t)E * sizeof(int);
    float* y      = (float*)ws;  ws += (size_t)N * 64 * sizeof(float);
    float* xbuf   = (float*)ws;  ws += (size_t)N * 64 * sizeof(float);

    int scanB = (N + 255) / 256;

    hipMemsetAsync(deg, 0, (size_t)N * sizeof(int), stream);
    k_deg<<<(E + 255) / 256, 256, 0, stream>>>(col, E, deg);
    k_dinv<<<(N + 255) / 256, 256, 0, stream>>>(deg, N, dinv);
    k_scan1<<<scanB, 256, 0, stream>>>(deg, N, starts, bsums);
    k_scan2<<<1, 512, 0, stream>>>(bsums, scanB);
    k_scan3<<<scanB, 256, 0, stream>>>(starts, bsums, N, E, deg /* cursor */);
    k_bucket<<<(E + 255) / 256, 256, 0, stream>>>(row, col, E, deg /* cursor */, srcs);

    const float* xin = x;
    for (int l = 0; l < 3; ++l) {
        k_gemm_scale<<<(N + 15) / 16, 256, 0, stream>>>(xin, W[l], dinv, y, N);
        k_agg<<<((size_t)N * 64 + 255) / 256, 256, 0, stream>>>(starts, srcs, y, dinv, b[l], xbuf, N);
        xin = xbuf;
    }

    k_pool_readout<<<G, 256, 0, stream>>>(xbuf, batch, N, Wro, bro, (float*)d_out, C);
}

// Round 3
// 1429.276 us; speedup vs baseline: 1.3468x; 1.0697x over previous
//
#include <hip/hip_runtime.h>
#include <hip/hip_fp16.h>

// GCN: 3x (x = silu(Dinv A Dinv (x W) + b)) -> mean-pool -> relu(pooled@Wro+bro) -> log_softmax
// y = (x@W)*dinv[row] stored FP16; out[c] = dinv[c]*(sum_{r->c} y[r] + y[c]) + b; x' = silu(out) stored FP16.
// Edge aggregation via CSR (built once): srcs sorted by target node. FP32 accumulation everywhere.

__global__ void k_deg(const int* __restrict__ col, int E, int* __restrict__ deg) {
    int e = blockIdx.x * blockDim.x + threadIdx.x;
    if (e < E) atomicAdd(&deg[col[e]], 1);
}

__global__ void k_dinv(const int* __restrict__ deg, int N, float* __restrict__ dinv) {
    int i = blockIdx.x * blockDim.x + threadIdx.x;
    if (i < N) dinv[i] = rsqrtf((float)deg[i] + 1.0f);  // +1 = self loop
}

// ---- exclusive scan of deg -> starts ----
__global__ void k_scan1(const int* __restrict__ deg, int N, int* __restrict__ starts,
                        int* __restrict__ bsums) {
    __shared__ int s[256];
    int tid = threadIdx.x;
    int i = blockIdx.x * 256 + tid;
    int v = (i < N) ? deg[i] : 0;
    s[tid] = v;
    __syncthreads();
    for (int off = 1; off < 256; off <<= 1) {
        int t = (tid >= off) ? s[tid - off] : 0;
        __syncthreads();
        s[tid] += t;
        __syncthreads();
    }
    if (i < N) starts[i] = s[tid] - v;
    if (tid == 255) bsums[blockIdx.x] = s[255];
}

__global__ void k_scan2(int* __restrict__ bsums, int B) {  // B <= 512
    __shared__ int s[512];
    int tid = threadIdx.x;
    int v = (tid < B) ? bsums[tid] : 0;
    s[tid] = v;
    __syncthreads();
    for (int off = 1; off < 512; off <<= 1) {
        int t = (tid >= off) ? s[tid - off] : 0;
        __syncthreads();
        s[tid] += t;
        __syncthreads();
    }
    if (tid < B) bsums[tid] = s[tid] - v;
}

__global__ void k_scan3(int* __restrict__ starts, const int* __restrict__ bsums,
                        int N, int E, int* __restrict__ cursor) {
    int i = blockIdx.x * 256 + threadIdx.x;
    if (i < N) {
        int v = starts[i] + bsums[blockIdx.x];
        starts[i] = v;
        cursor[i] = v;
    }
    if (blockIdx.x == 0 && threadIdx.x == 0) starts[N] = E;
}

__global__ void k_bucket(const int* __restrict__ row, const int* __restrict__ col, int E,
                         int* __restrict__ cursor, int* __restrict__ srcs) {
    int e = blockIdx.x * blockDim.x + threadIdx.x;
    if (e < E) {
        int pos = atomicAdd(&cursor[col[e]], 1);
        srcs[pos] = row[e];
    }
}

// yh[row] = fp16((x[row] @ W) * dinv[row]); 16 rows per 256-thread block, W in LDS.
template <int IN_HALF>
__global__ void k_gemm_scale(const void* __restrict__ xin, const float* __restrict__ W,
                             const float* __restrict__ dinv, __half* __restrict__ yh, int N) {
    __shared__ float sW[64 * 64];
    __shared__ float sx[16 * 64];
    int tid = threadIdx.x;
    for (int k = tid; k < 64 * 64; k += 256) sW[k] = W[k];
    int base = blockIdx.x * 16;
    for (int idx = tid; idx < 512; idx += 256) {  // 16 rows x 32 pairs
        int rr = idx >> 5, c = idx & 31;
        int row = base + rr;
        float2 f = make_float2(0.f, 0.f);
        if (row < N) {
            if (IN_HALF) f = __half22float2(((const __half2*)xin)[(size_t)row * 32 + c]);
            else         f = ((const float2*)xin)[(size_t)row * 32 + c];
        }
        sx[rr * 64 + 2 * c]     = f.x;
        sx[rr * 64 + 2 * c + 1] = f.y;
    }
    __syncthreads();
    int r = tid >> 6, j = tid & 63;
    float a0 = 0.f, a1 = 0.f, a2 = 0.f, a3 = 0.f;
#pragma unroll
    for (int k = 0; k < 64; ++k) {
        float w = sW[k * 64 + j];
        a0 += sx[(r     ) * 64 + k] * w;
        a1 += sx[(r +  4) * 64 + k] * w;
        a2 += sx[(r +  8) * 64 + k] * w;
        a3 += sx[(r + 12) * 64 + k] * w;
    }
    int r0 = base + r;
    if (r0      < N) yh[(size_t)(r0     ) * 64 + j] = __float2half_rn(a0 * dinv[r0]);
    if (r0 +  4 < N) yh[(size_t)(r0 +  4) * 64 + j] = __float2half_rn(a1 * dinv[r0 + 4]);
    if (r0 +  8 < N) yh[(size_t)(r0 +  8) * 64 + j] = __float2half_rn(a2 * dinv[r0 + 8]);
    if (r0 + 12 < N) yh[(size_t)(r0 + 12) * 64 + j] = __float2half_rn(a3 * dinv[r0 + 12]);
}

// One wave per node. Lanes split 2x32: grp handles edges e+grp, e+2+grp, e+4+grp, e+6+grp.
// Each lane owns feature pair (2i, 2i+1) via __half2. FP32 accum, shfl-reduce across groups.
__global__ void k_agg(const int* __restrict__ starts, const int* __restrict__ srcs,
                      const __half2* __restrict__ yh2, const float* __restrict__ dinv,
                      const float* __restrict__ b, __half2* __restrict__ xh2, int N) {
    int wid = (blockIdx.x * blockDim.x + threadIdx.x) >> 6;
    if (wid >= N) return;
    int lane = threadIdx.x & 63;
    int grp = lane >> 5, i = lane & 31;
    int s = starts[wid], t = starts[wid + 1];
    float ax = 0.f, ay = 0.f;
    if (grp == 0) {  // self loop
        float2 sv = __half22float2(yh2[(size_t)wid * 32 + i]);
        ax = sv.x; ay = sv.y;
    }
    for (int e = s; e < t; e += 8) {
        int ea = e + grp, eb = e + 2 + grp, ec = e + 4 + grp, ed = e + 6 + grp;
        if (ea < t) { float2 v = __half22float2(yh2[(size_t)srcs[ea] * 32 + i]); ax += v.x; ay += v.y; }
        if (eb < t) { float2 v = __half22float2(yh2[(size_t)srcs[eb] * 32 + i]); ax += v.x; ay += v.y; }
        if (ec < t) { float2 v = __half22float2(yh2[(size_t)srcs[ec] * 32 + i]); ax += v.x; ay += v.y; }
        if (ed < t) { float2 v = __half22float2(yh2[(size_t)srcs[ed] * 32 + i]); ax += v.x; ay += v.y; }
    }
    ax += __shfl_xor(ax, 32);
    ay += __shfl_xor(ay, 32);
    if (grp == 0) {
        float d = dinv[wid];
        float2 bb = ((const float2*)b)[i];
        float vx = d * ax + bb.x;
        float vy = d * ay + bb.y;
        vx = vx / (1.f + __expf(-vx));
        vy = vy / (1.f + __expf(-vy));
        xh2[(size_t)wid * 32 + i] = __float22half2_rn(make_float2(vx, vy));
    }
}

// One block per graph: binary-search segment, mean-pool (fp32 accum), readout, log_softmax
__global__ void k_pool_readout(const __half2* __restrict__ xh2, const int* __restrict__ batch, int N,
                               const float* __restrict__ Wro, const float* __restrict__ bro,
                               float* __restrict__ out, int C) {
    int g = blockIdx.x;
    int tid = threadIdx.x, wave = tid >> 6, lane = tid & 63;
    int grp = lane >> 5, i = lane & 31;
    __shared__ float part[4][64];
    __shared__ float pooled[64];
    __shared__ float logits[32];
    int lo = 0, hb = N;
    while (lo < hb) { int m = (lo + hb) >> 1; if (batch[m] < g) lo = m + 1; else hb = m; }
    int lo2 = lo, hi2 = N;
    while (lo2 < hi2) { int m = (lo2 + hi2) >> 1; if (batch[m] < g + 1) lo2 = m + 1; else hi2 = m; }
    int hi = lo2;
    float ax = 0.f, ay = 0.f;
    for (int r = lo + wave * 2 + grp; r < hi; r += 8) {
        float2 v = __half22float2(xh2[(size_t)r * 32 + i]);
        ax += v.x; ay += v.y;
    }
    ax += __shfl_xor(ax, 32);
    ay += __shfl_xor(ay, 32);
    if (grp == 0) { part[wave][2 * i] = ax; part[wave][2 * i + 1] = ay; }
    __syncthreads();
    if (tid < 64) {
        float cnt = fmaxf((float)(hi - lo), 1.0f);
        pooled[tid] = (part[0][tid] + part[1][tid] + part[2][tid] + part[3][tid]) / cnt;
    }
    __syncthreads();
    if (tid < C) {
        float a = bro[tid];
        for (int k = 0; k < 64; ++k) a += pooled[k] * Wro[k * C + tid];
        logits[tid] = fmaxf(a, 0.f);
    }
    __syncthreads();
    if (tid == 0) {
        float m = -1e30f;
        for (int c = 0; c < C; ++c) m = fmaxf(m, logits[c]);
        float sum = 0.f;
        for (int c = 0; c < C; ++c) sum += __expf(logits[c] - m);
        float lse = m + __logf(sum);
        for (int c = 0; c < C; ++c) out[g * C + c] = logits[c] - lse;
    }
}

static inline size_t align256(size_t v) { return (v + 255) & ~(size_t)255; }

extern "C" void kernel_launch(void* const* d_in, const int* in_sizes, int n_in,
                              void* d_out, int out_size, void* d_ws, size_t ws_size,
                              hipStream_t stream) {
    const float* x    = (const float*)d_in[0];
    const int*   ei   = (const int*)d_in[1];
    const int*   batch= (const int*)d_in[2];
    const float* W[3] = {(const float*)d_in[4], (const float*)d_in[6], (const float*)d_in[8]};
    const float* b[3] = {(const float*)d_in[5], (const float*)d_in[7], (const float*)d_in[9]};
    const float* Wro  = (const float*)d_in[10];
    const float* bro  = (const float*)d_in[11];

    int N = in_sizes[2];
    int E = in_sizes[1] / 2;
    int C = in_sizes[10] / 64;
    int G = out_size / C;

    const int* row = ei;          // sources
    const int* col = ei + E;      // targets

    char* ws = (char*)d_ws;
    size_t off = 0;
    float* dinv   = (float*)(ws + off); off = align256(off + (size_t)N * 4);
    int*   deg    = (int*)(ws + off);   off = align256(off + (size_t)N * 4);   // reused as cursor
    int*   starts = (int*)(ws + off);   off = align256(off + (size_t)(N + 1) * 4);
    int*   bsums  = (int*)(ws + off);   off = align256(off + 512 * 4);
    int*   srcs   = (int*)(ws + off);   off = align256(off + (size_t)E * 4);
    __half* yh    = (__half*)(ws + off); off = align256(off + (size_t)N * 64 * 2);
    __half* xh    = (__half*)(ws + off); off = align256(off + (size_t)N * 64 * 2);

    int scanB = (N + 255) / 256;

    hipMemsetAsync(deg, 0, (size_t)N * sizeof(int), stream);
    k_deg<<<(E + 255) / 256, 256, 0, stream>>>(col, E, deg);
    k_dinv<<<(N + 255) / 256, 256, 0, stream>>>(deg, N, dinv);
    k_scan1<<<scanB, 256, 0, stream>>>(deg, N, starts, bsums);
    k_scan2<<<1, 512, 0, stream>>>(bsums, scanB);
    k_scan3<<<scanB, 256, 0, stream>>>(starts, bsums, N, E, deg /* cursor */);
    k_bucket<<<(E + 255) / 256, 256, 0, stream>>>(row, col, E, deg /* cursor */, srcs);

    int gemmB = (N + 15) / 16;
    int aggB  = (int)(((size_t)N * 64 + 255) / 256);

    k_gemm_scale<0><<<gemmB, 256, 0, stream>>>(x, W[0], dinv, yh, N);
    k_agg<<<aggB, 256, 0, stream>>>(starts, srcs, (const __half2*)yh, dinv, b[0], (__half2*)xh, N);
    k_gemm_scale<1><<<gemmB, 256, 0, stream>>>(xh, W[1], dinv, yh, N);
    k_agg<<<aggB, 256, 0, stream>>>(starts, srcs, (const __half2*)yh, dinv, b[1], (__half2*)xh, N);
    k_gemm_scale<1><<<gemmB, 256, 0, stream>>>(xh, W[2], dinv, yh, N);
    k_agg<<<aggB, 256, 0, stream>>>(starts, srcs, (const __half2*)yh, dinv, b[2], (__half2*)xh, N);

    k_pool_readout<<<G, 256, 0, stream>>>((const __half2*)xh, batch, N, Wro, bro, (float*)d_out, C);
}

// Round 4
// 481.679 us; speedup vs baseline: 3.9963x; 2.9673x over previous
//
#include <hip/hip_runtime.h>
#include <hip/hip_fp16.h>

// GCN: 3x (x = silu(Dinv A Dinv (x W) + b)) -> mean-pool -> relu(pooled@Wro+bro) -> log_softmax
// y = (x@W)*dinv[row] fp16; out[c] = dinv[c]*(sum_{r->c} y[r] + y[c]) + b; x' = silu(out) fp16.
// CSR (srcs sorted by target) built once per pass. FP32 accumulation everywhere.
// GEMM via MFMA 16x16x32 f16: W-fragments in registers, persistent waves, no LDS in loop.

typedef _Float16 half8 __attribute__((ext_vector_type(8)));
typedef float float4v __attribute__((ext_vector_type(4)));

__global__ void k_deg(const int* __restrict__ col, int E, int* __restrict__ deg) {
    int e = blockIdx.x * blockDim.x + threadIdx.x;
    if (e < E) atomicAdd(&deg[col[e]], 1);
}

// exclusive scan of deg (block-local) + dinv = rsqrt(deg+1)
__global__ void k_scan1(const int* __restrict__ deg, int N, int* __restrict__ starts,
                        int* __restrict__ bsums, float* __restrict__ dinv) {
    __shared__ int s[256];
    int tid = threadIdx.x;
    int i = blockIdx.x * 256 + tid;
    int v = (i < N) ? deg[i] : 0;
    if (i < N) dinv[i] = rsqrtf((float)v + 1.0f);
    s[tid] = v;
    __syncthreads();
    for (int off = 1; off < 256; off <<= 1) {
        int t = (tid >= off) ? s[tid - off] : 0;
        __syncthreads();
        s[tid] += t;
        __syncthreads();
    }
    if (i < N) starts[i] = s[tid] - v;
    if (tid == 255) bsums[blockIdx.x] = s[255];
}

__global__ void k_scan2(int* __restrict__ bsums, int B) {  // B <= 512
    __shared__ int s[512];
    int tid = threadIdx.x;
    int v = (tid < B) ? bsums[tid] : 0;
    s[tid] = v;
    __syncthreads();
    for (int off = 1; off < 512; off <<= 1) {
        int t = (tid >= off) ? s[tid - off] : 0;
        __syncthreads();
        s[tid] += t;
        __syncthreads();
    }
    if (tid < B) bsums[tid] = s[tid] - v;
}

__global__ void k_scan3(int* __restrict__ starts, const int* __restrict__ bsums,
                        int N, int E, int* __restrict__ cursor) {
    int i = blockIdx.x * 256 + threadIdx.x;
    if (i < N) {
        int v = starts[i] + bsums[blockIdx.x];
        starts[i] = v;
        cursor[i] = v;
    }
    if (blockIdx.x == 0 && threadIdx.x == 0) starts[N] = E;
}

__global__ void k_bucket(const int* __restrict__ row, const int* __restrict__ col, int E,
                         int* __restrict__ cursor, int* __restrict__ srcs) {
    int e = blockIdx.x * blockDim.x + threadIdx.x;
    if (e < E) {
        int pos = atomicAdd(&cursor[col[e]], 1);
        srcs[pos] = row[e];
    }
}

// MFMA GEMM: yh[r] = fp16((x[r] @ W) * dinv[r]).
// Per wave: 16-row tile, 4 col-tiles x 2 K-steps of mfma_f32_16x16x32_f16.
// A layout: lane holds row (lane&15), k = (lane>>4)*8 + j.
// B layout: lane holds col (lane&15), k = (lane>>4)*8 + j.
// C layout: lane holds col (lane&15), row = (lane>>4)*4 + q.
template <int IN_HALF>
__global__ __launch_bounds__(256) void k_gemm(const void* __restrict__ xin,
                                              const float* __restrict__ W,
                                              const float* __restrict__ dinv,
                                              __half* __restrict__ yh, int N) {
    __shared__ float sW[64 * 64];
    int tid = threadIdx.x;
    for (int k = tid; k < 4096; k += 256) sW[k] = W[k];
    __syncthreads();
    int lane = tid & 63, wv = tid >> 6;
    int c16 = lane & 15, kg = lane >> 4;   // kg = k-group 0..3
    half8 bf[4][2];
#pragma unroll
    for (int ct = 0; ct < 4; ++ct)
#pragma unroll
        for (int ks = 0; ks < 2; ++ks)
#pragma unroll
            for (int j = 0; j < 8; ++j)
                bf[ct][ks][j] = (_Float16)sW[(ks * 32 + kg * 8 + j) * 64 + ct * 16 + c16];

    int tiles = (N + 15) >> 4;
    for (int t = blockIdx.x * 4 + wv; t < tiles; t += gridDim.x * 4) {
        int base = t << 4;
        int arow = base + c16;
        half8 af0, af1;
        if (arow < N) {
            if (IN_HALF) {
                const __half* xh = (const __half*)xin;
                af0 = *(const half8*)(xh + (size_t)arow * 64 + kg * 8);
                af1 = *(const half8*)(xh + (size_t)arow * 64 + 32 + kg * 8);
            } else {
                const float* xf = (const float*)xin;
                float4 u0 = *(const float4*)(xf + (size_t)arow * 64 + kg * 8);
                float4 u1 = *(const float4*)(xf + (size_t)arow * 64 + kg * 8 + 4);
                float4 u2 = *(const float4*)(xf + (size_t)arow * 64 + 32 + kg * 8);
                float4 u3 = *(const float4*)(xf + (size_t)arow * 64 + 32 + kg * 8 + 4);
                af0[0]=(_Float16)u0.x; af0[1]=(_Float16)u0.y; af0[2]=(_Float16)u0.z; af0[3]=(_Float16)u0.w;
                af0[4]=(_Float16)u1.x; af0[5]=(_Float16)u1.y; af0[6]=(_Float16)u1.z; af0[7]=(_Float16)u1.w;
                af1[0]=(_Float16)u2.x; af1[1]=(_Float16)u2.y; af1[2]=(_Float16)u2.z; af1[3]=(_Float16)u2.w;
                af1[4]=(_Float16)u3.x; af1[5]=(_Float16)u3.y; af1[6]=(_Float16)u3.z; af1[7]=(_Float16)u3.w;
            }
        } else {
#pragma unroll
            for (int j = 0; j < 8; ++j) { af0[j] = (_Float16)0.f; af1[j] = (_Float16)0.f; }
        }
#pragma unroll
        for (int ct = 0; ct < 4; ++ct) {
            float4v c = {0.f, 0.f, 0.f, 0.f};
            c = __builtin_amdgcn_mfma_f32_16x16x32_f16(af0, bf[ct][0], c, 0, 0, 0);
            c = __builtin_amdgcn_mfma_f32_16x16x32_f16(af1, bf[ct][1], c, 0, 0, 0);
#pragma unroll
            for (int q = 0; q < 4; ++q) {
                int rr = base + kg * 4 + q;
                if (rr < N) yh[(size_t)rr * 64 + ct * 16 + c16] = __float2half_rn(c[q] * dinv[rr]);
            }
        }
    }
}

// One wave per node. 8 groups x 8 lanes; lane (g,i) loads 16B chunk i of row srcs[e+g]
// -> 8 rows per wave-instruction, 16 rows in flight per iteration. shfl-xor reduce.
__global__ __launch_bounds__(256) void k_agg(const int* __restrict__ starts,
                                             const int* __restrict__ srcs,
                                             const __half* __restrict__ yh,
                                             const float* __restrict__ dinv,
                                             const float* __restrict__ b,
                                             __half* __restrict__ xh, int N) {
    int wid = (blockIdx.x * blockDim.x + threadIdx.x) >> 6;
    if (wid >= N) return;
    int lane = threadIdx.x & 63;
    int g = lane >> 3, i = lane & 7;
    const float4* y4 = (const float4*)yh;   // row = 8 float4 chunks
    float acc[8] = {0.f,0.f,0.f,0.f,0.f,0.f,0.f,0.f};

    if (g == 0) {  // self loop
        float4 raw = y4[(size_t)wid * 8 + i];
        const __half2* h = (const __half2*)&raw;
#pragma unroll
        for (int p = 0; p < 4; ++p) {
            float2 f = __half22float2(h[p]);
            acc[2 * p] += f.x; acc[2 * p + 1] += f.y;
        }
    }
    int s = starts[wid], t = starts[wid + 1];
    for (int e = s; e < t; e += 16) {
        int e0 = e + g, e1 = e + 8 + g;
        if (e0 < t) {
            float4 raw = y4[(size_t)srcs[e0] * 8 + i];
            const __half2* h = (const __half2*)&raw;
#pragma unroll
            for (int p = 0; p < 4; ++p) {
                float2 f = __half22float2(h[p]);
                acc[2 * p] += f.x; acc[2 * p + 1] += f.y;
            }
        }
        if (e1 < t) {
            float4 raw = y4[(size_t)srcs[e1] * 8 + i];
            const __half2* h = (const __half2*)&raw;
#pragma unroll
            for (int p = 0; p < 4; ++p) {
                float2 f = __half22float2(h[p]);
                acc[2 * p] += f.x; acc[2 * p + 1] += f.y;
            }
        }
    }
#pragma unroll
    for (int off = 8; off <= 32; off <<= 1)
#pragma unroll
        for (int f = 0; f < 8; ++f) acc[f] += __shfl_xor(acc[f], off);

    if (g == 0) {
        float d = dinv[wid];
        float4 b0 = ((const float4*)b)[2 * i];
        float4 b1 = ((const float4*)b)[2 * i + 1];
        float bb[8] = {b0.x, b0.y, b0.z, b0.w, b1.x, b1.y, b1.z, b1.w};
        float o[8];
#pragma unroll
        for (int f = 0; f < 8; ++f) {
            float v = d * acc[f] + bb[f];
            o[f] = v / (1.f + __expf(-v));
        }
        float4 outv;
        __half2* oh = (__half2*)&outv;
#pragma unroll
        for (int p = 0; p < 4; ++p) oh[p] = __float22half2_rn(make_float2(o[2 * p], o[2 * p + 1]));
        ((float4*)xh)[(size_t)wid * 8 + i] = outv;
    }
}

// One block per graph: binary-search segment, mean-pool (fp32 accum), readout, log_softmax
__global__ void k_pool_readout(const __half2* __restrict__ xh2, const int* __restrict__ batch, int N,
                               const float* __restrict__ Wro, const float* __restrict__ bro,
                               float* __restrict__ out, int C) {
    int g = blockIdx.x;
    int tid = threadIdx.x, wave = tid >> 6, lane = tid & 63;
    int grp = lane >> 5, i = lane & 31;
    __shared__ float part[4][64];
    __shared__ float pooled[64];
    __shared__ float logits[32];
    int lo = 0, hb = N;
    while (lo < hb) { int m = (lo + hb) >> 1; if (batch[m] < g) lo = m + 1; else hb = m; }
    int lo2 = lo, hi2 = N;
    while (lo2 < hi2) { int m = (lo2 + hi2) >> 1; if (batch[m] < g + 1) lo2 = m + 1; else hi2 = m; }
    int hi = lo2;
    float ax = 0.f, ay = 0.f;
    for (int r = lo + wave * 2 + grp; r < hi; r += 8) {
        float2 v = __half22float2(xh2[(size_t)r * 32 + i]);
        ax += v.x; ay += v.y;
    }
    ax += __shfl_xor(ax, 32);
    ay += __shfl_xor(ay, 32);
    if (grp == 0) { part[wave][2 * i] = ax; part[wave][2 * i + 1] = ay; }
    __syncthreads();
    if (tid < 64) {
        float cnt = fmaxf((float)(hi - lo), 1.0f);
        pooled[tid] = (part[0][tid] + part[1][tid] + part[2][tid] + part[3][tid]) / cnt;
    }
    __syncthreads();
    if (tid < C) {
        float a = bro[tid];
        for (int k = 0; k < 64; ++k) a += pooled[k] * Wro[k * C + tid];
        logits[tid] = fmaxf(a, 0.f);
    }
    __syncthreads();
    if (tid == 0) {
        float m = -1e30f;
        for (int c = 0; c < C; ++c) m = fmaxf(m, logits[c]);
        float sum = 0.f;
        for (int c = 0; c < C; ++c) sum += __expf(logits[c] - m);
        float lse = m + __logf(sum);
        for (int c = 0; c < C; ++c) out[g * C + c] = logits[c] - lse;
    }
}

static inline size_t align256(size_t v) { return (v + 255) & ~(size_t)255; }

extern "C" void kernel_launch(void* const* d_in, const int* in_sizes, int n_in,
                              void* d_out, int out_size, void* d_ws, size_t ws_size,
                              hipStream_t stream) {
    const float* x    = (const float*)d_in[0];
    const int*   ei   = (const int*)d_in[1];
    const int*   batch= (const int*)d_in[2];
    const float* W[3] = {(const float*)d_in[4], (const float*)d_in[6], (const float*)d_in[8]};
    const float* b[3] = {(const float*)d_in[5], (const float*)d_in[7], (const float*)d_in[9]};
    const float* Wro  = (const float*)d_in[10];
    const float* bro  = (const float*)d_in[11];

    int N = in_sizes[2];
    int E = in_sizes[1] / 2;
    int C = in_sizes[10] / 64;
    int G = out_size / C;

    const int* row = ei;          // sources
    const int* col = ei + E;      // targets

    char* ws = (char*)d_ws;
    size_t off = 0;
    float* dinv   = (float*)(ws + off); off = align256(off + (size_t)N * 4);
    int*   deg    = (int*)(ws + off);   off = align256(off + (size_t)N * 4);   // reused as cursor
    int*   starts = (int*)(ws + off);   off = align256(off + (size_t)(N + 1) * 4);
    int*   bsums  = (int*)(ws + off);   off = align256(off + 512 * 4);
    int*   srcs   = (int*)(ws + off);   off = align256(off + (size_t)E * 4);
    __half* yh    = (__half*)(ws + off); off = align256(off + (size_t)N * 64 * 2);
    __half* xh    = (__half*)(ws + off); off = align256(off + (size_t)N * 64 * 2);

    int scanB = (N + 255) / 256;

    hipMemsetAsync(deg, 0, (size_t)N * sizeof(int), stream);
    k_deg<<<(E + 255) / 256, 256, 0, stream>>>(col, E, deg);
    k_scan1<<<scanB, 256, 0, stream>>>(deg, N, starts, bsums, dinv);
    k_scan2<<<1, 512, 0, stream>>>(bsums, scanB);
    k_scan3<<<scanB, 256, 0, stream>>>(starts, bsums, N, E, deg /* cursor */);
    k_bucket<<<(E + 255) / 256, 256, 0, stream>>>(row, col, E, deg /* cursor */, srcs);

    int aggB = (N + 3) / 4;   // 4 waves (nodes) per 256-thread block

    k_gemm<0><<<512, 256, 0, stream>>>(x, W[0], dinv, yh, N);
    k_agg<<<aggB, 256, 0, stream>>>(starts, srcs, yh, dinv, b[0], xh, N);
    k_gemm<1><<<512, 256, 0, stream>>>(xh, W[1], dinv, yh, N);
    k_agg<<<aggB, 256, 0, stream>>>(starts, srcs, yh, dinv, b[1], xh, N);
    k_gemm<1><<<512, 256, 0, stream>>>(xh, W[2], dinv, yh, N);
    k_agg<<<aggB, 256, 0, stream>>>(starts, srcs, yh, dinv, b[2], xh, N);

    k_pool_readout<<<G, 256, 0, stream>>>((const __half2*)xh, batch, N, Wro, bro, (float*)d_out, C);
}